// Round 5
// baseline (50744.904 us; speedup 1.0000x reference)
//
#include <hip/hip_runtime.h>

// Tanh RNN: B=64, S=2048, I=H=512, fp32 in/out.
//
// rnn (round 5): 16 WGs = 8 pairs (blk, blk^8) -> same XCD under %8 round-robin.
// Pair r owns batch rows r*8..+8; half c owns output cols c*256..+256 with its
// W_hh half register-resident (128 VGPR/lane, ALL indices compile-time).
// h_t lives in write-once global slot[t]; BOTH halves read via sc0 poll loads
// (L2-coherent within XCD). Primary lanes store plain (fast L2 path); duplicate
// lanes store sc0 sc1 (MALL) for placement-independent correctness; consumers
// escalate to MALL polls per-step after 8 failed fast sweeps (non-sticky).
// No LDS, no barriers, no fences.

typedef _Float16 half8 __attribute__((ext_vector_type(8)));
typedef _Float16 half4 __attribute__((ext_vector_type(4)));
typedef float f32x4 __attribute__((ext_vector_type(4)));
typedef unsigned int u32x4 __attribute__((ext_vector_type(4)));
typedef unsigned long long u64;

#define S_SZ 2048
#define OUT1_OFF 67108864ull   // S*B*H floats

// workspace offsets (bytes); ~269.55 MB total
#define XP_OFF    0ull              // 2048*64*512*2   = 134217728
#define SLOT_OFF  134217728ull      // 2049*16*512*8   = 134283264
#define WHH_OFF   268500992ull      // 524288
#define WIH_OFF   269025280ull      // 524288
#define BIAS_OFF  269549568ull      // 2048

#define POISON    0x7FFF7FFF7FFF7FFFull
#define POISON32  0x7FFF7FFFu

__device__ __forceinline__ float fast_tanh(float x) {
    float a = exp2f(fminf(fmaxf(x * 2.8853900817779268f, -30.f), 30.f));
    return (a - 1.0f) * __builtin_amdgcn_rcpf(a + 1.0f);
}

// L1-bypass load: coherent at L2 (same-XCD coherence point)
__device__ __forceinline__ u32x4 load_b128_sc0(const u64* p) {
    u32x4 r;
    asm volatile("global_load_dwordx4 %0, %1, off sc0" : "=v"(r) : "v"(p) : "memory");
    return r;
}
// device-scope load: bypasses L1+L2, served by MALL
__device__ __forceinline__ u32x4 load_b128_dev(const u64* p) {
    u32x4 r;
    asm volatile("global_load_dwordx4 %0, %1, off sc0 sc1" : "=v"(r) : "v"(p) : "memory");
    return r;
}
__device__ __forceinline__ void store_b64_plain(u64* p, u64 v) {
    asm volatile("global_store_dwordx2 %0, %1, off" :: "v"(p), "v"(v) : "memory");
}
__device__ __forceinline__ void store_b64_dev(u64* p, u64 v) {
    asm volatile("global_store_dwordx2 %0, %1, off sc0 sc1" :: "v"(p), "v"(v) : "memory");
}

__global__ void prep_kernel(const float* __restrict__ wih, const float* __restrict__ whh,
                            const float* __restrict__ bih, const float* __restrict__ bhh,
                            _Float16* __restrict__ wih16, _Float16* __restrict__ whh16,
                            float* __restrict__ bias)
{
    const int i = blockIdx.x * 256 + threadIdx.x;   // 1024 blocks -> 262144
    wih16[i] = (_Float16)wih[i];
    whh16[i] = (_Float16)whh[i];
    if (i < 512) bias[i] = bih[i] + bhh[i];
}

// poison all 2049*16 sub-slots; slot0 = packed fp16 state.
// sub-slot (t, r, c) base qword = (t*16 + r*2 + c)*512; layout [8 rows][64 qwords].
__global__ void slotinit_kernel(const float* __restrict__ state, u64* __restrict__ slotq)
{
    const int base = (blockIdx.x * 256 + threadIdx.x) * 4;   // 16392 blocks
    #pragma unroll
    for (int k = 0; k < 4; ++k) {
        const int q = base + k;
        if (q >= 16785408) return;
        if (q < 8192) {
            const int rc = q >> 9, within = q & 511;
            const int r = rc >> 1, c = rc & 1;
            const int brow = within >> 6, j4 = within & 63;
            const float4 v = *reinterpret_cast<const float4*>(
                state + (size_t)(r * 8 + brow) * 512 + c * 256 + j4 * 4);
            union { _Float16 h[4]; u64 u; } p;
            p.h[0] = (_Float16)v.x; p.h[1] = (_Float16)v.y;
            p.h[2] = (_Float16)v.z; p.h[3] = (_Float16)v.w;
            slotq[q] = p.u;
        } else {
            slotq[q] = POISON;
        }
    }
}

// ---------------- input projection GEMM (verified rounds 3-4) ----------------
__global__ __launch_bounds__(512, 1) void xproj_kernel(
    const float* __restrict__ inputs, const _Float16* __restrict__ wih16,
    const float* __restrict__ bias, _Float16* __restrict__ xp16)
{
    __shared__ _Float16 Alds[64 * 512];
    const int s = blockIdx.x;

    for (int idx = threadIdx.x; idx < 64 * 128; idx += 512) {
        const int row = idx >> 7, chunk = idx & 127;
        const float4 v = *reinterpret_cast<const float4*>(
            inputs + ((size_t)row * S_SZ + s) * 512 + chunk * 4);
        half4 hv;
        hv[0] = (_Float16)v.x; hv[1] = (_Float16)v.y;
        hv[2] = (_Float16)v.z; hv[3] = (_Float16)v.w;
        const int bc = (chunk * 8) ^ ((row & 7) << 4);
        *reinterpret_cast<half4*>(reinterpret_cast<char*>(Alds) + row * 1024 + bc) = hv;
    }
    __syncthreads();

    const int lane = threadIdx.x & 63, w = threadIdx.x >> 6;
    const int l15 = lane & 15, lg = lane >> 4;

    f32x4 acc[4][4];
    #pragma unroll
    for (int m = 0; m < 4; ++m)
        #pragma unroll
        for (int n = 0; n < 4; ++n)
            acc[m][n] = 0.0f;

    for (int kk = 0; kk < 16; ++kk) {
        half8 af[4], bf[4];
        #pragma unroll
        for (int m = 0; m < 4; ++m) {
            const int row = m * 16 + l15;
            const int bc = (kk * 64 + lg * 16) ^ ((row & 7) << 4);
            af[m] = *reinterpret_cast<const half8*>(
                reinterpret_cast<const char*>(Alds) + row * 1024 + bc);
        }
        #pragma unroll
        for (int n = 0; n < 4; ++n) {
            const int col = w * 64 + n * 16 + l15;
            bf[n] = *reinterpret_cast<const half8*>(wih16 + (size_t)col * 512 + kk * 32 + lg * 8);
        }
        #pragma unroll
        for (int m = 0; m < 4; ++m)
            #pragma unroll
            for (int n = 0; n < 4; ++n)
                acc[m][n] = __builtin_amdgcn_mfma_f32_16x16x32_f16(bf[n], af[m], acc[m][n], 0, 0, 0);
    }

    #pragma unroll
    for (int m = 0; m < 4; ++m) {
        const int brow = m * 16 + l15;
        #pragma unroll
        for (int n = 0; n < 4; ++n) {
            const int j0 = w * 64 + n * 16 + lg * 4;
            const float4 bv = *reinterpret_cast<const float4*>(bias + j0);
            half4 hv;
            hv[0] = (_Float16)(acc[m][n][0] + bv.x);
            hv[1] = (_Float16)(acc[m][n][1] + bv.y);
            hv[2] = (_Float16)(acc[m][n][2] + bv.z);
            hv[3] = (_Float16)(acc[m][n][3] + bv.w);
            *reinterpret_cast<half4*>(xp16 + ((size_t)s * 64 + brow) * 512 + j0) = hv;
        }
    }
}

// ---------------- persistent recurrence ----------------
__global__ __launch_bounds__(512, 2) void rnn_step_kernel(
    const _Float16* __restrict__ whh16, const _Float16* __restrict__ xp16,
    u64* __restrict__ slotq, float* __restrict__ out)
{
    const int blk = blockIdx.x;           // 0..15
    const int c = blk >> 3, r = blk & 7;  // peer = blk^8 (same XCD under %8 rr)
    const int tid = threadIdx.x;
    const int lane = tid & 63, w = tid >> 6;   // 8 waves
    const int l15 = lane & 15, lg = lane >> 4;
    const int row8 = l15 & 7;                  // batch row within pair (dup for l15>=8)
    const bool primary = (l15 < 8);

    // W_hh half, register-resident. ALL indices compile-time; c only in address.
    // wk0[jt][i]: j = c*256 + w*32 + jt*16 + l15, k = i*32 + lg*8 .. +8
    // wk1[jt][i]: same j,     k = 256 + i*32 + lg*8 .. +8
    half8 wk0[2][8], wk1[2][8];
    {
        const _Float16* wj = whh16 + (size_t)(c * 256 + w * 32 + l15) * 512 + lg * 8;
        #pragma unroll
        for (int jt = 0; jt < 2; ++jt) {
            const _Float16* wj2 = wj + jt * 16 * 512;
            #pragma unroll
            for (int i = 0; i < 8; ++i) {
                wk0[jt][i] = *reinterpret_cast<const half8*>(wj2 + i * 32);
                wk1[jt][i] = *reinterpret_cast<const half8*>(wj2 + 256 + i * 32);
            }
        }
    }

    const int xrow = r * 8 + row8;
    // xp for t=0
    u64 xq0, xq1;
    {
        const _Float16* xpp = xp16 + (size_t)xrow * 512 + c * 256 + w * 32 + lg * 4;
        xq0 = *reinterpret_cast<const u64*>(xpp);
        xq1 = *reinterpret_cast<const u64*>(xpp + 16);
    }

    const int qin_off = row8 * 64 + lg * 2;
    const int qout_off = row8 * 64 + w * 8 + lg;

    long budget = 2000000L;   // anti-hang; never hit if either path works

    #pragma unroll 1
    for (int t = 0; t < S_SZ; ++t) {
        // ---- poll-read all 512 k of h_t (both halves; write-once slot) ----
        const u64* b0 = slotq + ((size_t)t * 16 + r * 2) * 512 + qin_off;
        u32x4 pv[16];
        int sweep = 0;
        for (;;) {
            if (sweep < 8) {
                #pragma unroll
                for (int i = 0; i < 8; ++i) {
                    pv[i]     = load_b128_sc0(b0 + i * 8);
                    pv[8 + i] = load_b128_sc0(b0 + 512 + i * 8);
                }
            } else {  // escalate: MALL-coherent polls (cross-XCD placement)
                #pragma unroll
                for (int i = 0; i < 8; ++i) {
                    pv[i]     = load_b128_dev(b0 + i * 8);
                    pv[8 + i] = load_b128_dev(b0 + 512 + i * 8);
                }
            }
            asm volatile("s_waitcnt vmcnt(0)"
                : "+v"(pv[0]), "+v"(pv[1]), "+v"(pv[2]), "+v"(pv[3]),
                  "+v"(pv[4]), "+v"(pv[5]), "+v"(pv[6]), "+v"(pv[7]),
                  "+v"(pv[8]), "+v"(pv[9]), "+v"(pv[10]), "+v"(pv[11]),
                  "+v"(pv[12]), "+v"(pv[13]), "+v"(pv[14]), "+v"(pv[15])
                :: "memory");
            bool ok = true;
            #pragma unroll
            for (int i = 0; i < 16; ++i)
                ok &= (pv[i][0] != POISON32) & (pv[i][1] != POISON32) &
                      (pv[i][2] != POISON32) & (pv[i][3] != POISON32);
            if (__all(ok)) break;
            ++sweep;
            if (--budget < 0) break;
        }

        // ---- MFMA: acc_jt[j-quad][brow] += W[j][k] * h[brow][k] ----
        f32x4 acc0 = 0.0f, acc1 = 0.0f;
        #pragma unroll
        for (int i = 0; i < 8; ++i) {
            union { u32x4 v; half8 h; } h0, h1;
            h0.v = pv[i]; h1.v = pv[8 + i];
            acc0 = __builtin_amdgcn_mfma_f32_16x16x32_f16(wk0[0][i], h0.h, acc0, 0, 0, 0);
            acc1 = __builtin_amdgcn_mfma_f32_16x16x32_f16(wk0[1][i], h0.h, acc1, 0, 0, 0);
            acc0 = __builtin_amdgcn_mfma_f32_16x16x32_f16(wk1[0][i], h1.h, acc0, 0, 0, 0);
            acc1 = __builtin_amdgcn_mfma_f32_16x16x32_f16(wk1[1][i], h1.h, acc1, 0, 0, 0);
        }

        // ---- prefetch xp for t+1 (latency hides under tanh/stores) ----
        u64 xn0 = 0, xn1 = 0;
        if (t + 1 < S_SZ) {
            const _Float16* xpp = xp16 + ((size_t)(t + 1) * 64 + xrow) * 512 + c * 256 + w * 32 + lg * 4;
            xn0 = *reinterpret_cast<const u64*>(xpp);
            xn1 = *reinterpret_cast<const u64*>(xpp + 16);
        }

        // ---- tanh + pack ----
        union { _Float16 h[4]; u64 u; } x0, x1, p0, p1;
        x0.u = xq0; x1.u = xq1;
        f32x4 f0, f1;
        #pragma unroll
        for (int q = 0; q < 4; ++q) {
            f0[q] = fast_tanh(acc0[q] + (float)x0.h[q]);
            f1[q] = fast_tanh(acc1[q] + (float)x1.h[q]);
            p0.h[q] = (_Float16)f0[q];
            p1.h[q] = (_Float16)f1[q];
        }

        // ---- publish h_{t+1}: primary lanes -> L2 (fast), dup lanes -> MALL ----
        u64* qo = slotq + ((size_t)(t + 1) * 16 + r * 2 + c) * 512 + qout_off;
        if (primary) {
            store_b64_plain(qo, p0.u);
            store_b64_plain(qo + 4, p1.u);
        } else {  // identical values, device-visible path
            store_b64_dev(qo, p0.u);
            store_b64_dev(qo + 4, p1.u);
        }

        // ---- fp32 outputs (primary lanes only) ----
        if (primary) {
            float* orow = out + ((size_t)t * 64 + xrow) * 512 + c * 256 + w * 32 + lg * 4;
            *reinterpret_cast<f32x4*>(orow) = f0;
            *reinterpret_cast<f32x4*>(orow + 16) = f1;
            if (t == S_SZ - 1) {
                const int j0 = c * 256 + w * 32 + lg * 4;
                #pragma unroll
                for (int q = 0; q < 4; ++q) {
                    out[OUT1_OFF + (size_t)(j0 + q) * 64 + xrow] = f0[q];
                    out[OUT1_OFF + (size_t)(j0 + 16 + q) * 64 + xrow] = f1[q];
                }
            }
        }

        xq0 = xn0; xq1 = xn1;
    }
}

extern "C" void kernel_launch(void* const* d_in, const int* in_sizes, int n_in,
                              void* d_out, int out_size, void* d_ws, size_t ws_size,
                              hipStream_t stream)
{
    const float* inputs = (const float*)d_in[0];
    const float* state  = (const float*)d_in[1];
    const float* w_ih   = (const float*)d_in[2];
    const float* b_ih   = (const float*)d_in[3];
    const float* w_hh   = (const float*)d_in[4];
    const float* b_hh   = (const float*)d_in[5];
    float* out = (float*)d_out;
    char* ws = (char*)d_ws;

    _Float16* xp16  = (_Float16*)(ws + XP_OFF);
    u64*      slotq = (u64*)(ws + SLOT_OFF);
    _Float16* whh16 = (_Float16*)(ws + WHH_OFF);
    _Float16* wih16 = (_Float16*)(ws + WIH_OFF);
    float*    bias  = (float*)(ws + BIAS_OFF);

    slotinit_kernel<<<16392, 256, 0, stream>>>(state, slotq);
    prep_kernel<<<1024, 256, 0, stream>>>(w_ih, w_hh, b_ih, b_hh, wih16, whh16, bias);
    xproj_kernel<<<S_SZ, 512, 0, stream>>>(inputs, wih16, bias, xp16);
    rnn_step_kernel<<<16, 512, 0, stream>>>(whh16, xp16, slotq, out);
}

// Round 6
// 7685.580 us; speedup vs baseline: 6.6026x; 6.6026x over previous
//
#include <hip/hip_runtime.h>

// Tanh RNN: B=64, S=2048, I=H=512, fp32 in/out.
//
// Round 6: ZERO inter-WG communication. 8 WGs; WG r owns batch rows r*8..+8
// and computes the FULL recurrence for them. W_hh is CU-resident:
//   - k =   0..383 : register fragments (96 half8 per lane = 384 VGPR)
//   - k = 384..511 : LDS (16 chunks, 131 KB)
// h double-buffers in LDS (17 KB); one __syncthreads per step. 4 waves,
// wave w owns output cols j in [w*128, w*128+128). MFMA 16x16x32_f16 with
// batch rows in the 16-col D dim (8 real + 8 dup lanes).

typedef _Float16 half8 __attribute__((ext_vector_type(8)));
typedef _Float16 half4 __attribute__((ext_vector_type(4)));
typedef float f32x4 __attribute__((ext_vector_type(4)));
typedef unsigned long long u64;

#define S_SZ 2048
#define OUT1_OFF 67108864ull   // S*B*H floats

// workspace offsets (bytes)
#define XP_OFF    0ull              // 2048*64*512*2 = 134217728
#define WHH_OFF   134217728ull      // 524288
#define WIH_OFF   134742016ull      // 524288
#define BIAS_OFF  135266304ull      // 2048

// LDS geometry (dynamic)
#define WCHUNK    8208              // 512 j * 16B + 16 pad
#define NCHUNK    16                // (kk 12..15) x (lg 0..3)
#define HSTRIDE   1072              // 512*2 + 48 pad
#define HBUF_SZ   8576              // 8 rows * 1072
#define WLDS_SZ   131328            // 16*8208
#define SMEM_SZ   148480            // WLDS_SZ + 2*HBUF_SZ

__device__ __forceinline__ float fast_tanh(float x) {
    // |x| <= ~16 here (bounded pre-activation), so no clamping needed
    float a = exp2f(x * 2.8853900817779268f);
    return (a - 1.0f) * __builtin_amdgcn_rcpf(a + 1.0f);
}

__global__ void prep_kernel(const float* __restrict__ wih, const float* __restrict__ whh,
                            const float* __restrict__ bih, const float* __restrict__ bhh,
                            _Float16* __restrict__ wih16, _Float16* __restrict__ whh16,
                            float* __restrict__ bias)
{
    const int i = blockIdx.x * 256 + threadIdx.x;   // 1024 blocks -> 262144
    wih16[i] = (_Float16)wih[i];
    whh16[i] = (_Float16)whh[i];
    if (i < 512) bias[i] = bih[i] + bhh[i];
}

// ---------------- input projection GEMM (verified rounds 3-5) ----------------
__global__ __launch_bounds__(512, 1) void xproj_kernel(
    const float* __restrict__ inputs, const _Float16* __restrict__ wih16,
    const float* __restrict__ bias, _Float16* __restrict__ xp16)
{
    __shared__ _Float16 Alds[64 * 512];
    const int s = blockIdx.x;

    for (int idx = threadIdx.x; idx < 64 * 128; idx += 512) {
        const int row = idx >> 7, chunk = idx & 127;
        const float4 v = *reinterpret_cast<const float4*>(
            inputs + ((size_t)row * S_SZ + s) * 512 + chunk * 4);
        half4 hv;
        hv[0] = (_Float16)v.x; hv[1] = (_Float16)v.y;
        hv[2] = (_Float16)v.z; hv[3] = (_Float16)v.w;
        const int bc = (chunk * 8) ^ ((row & 7) << 4);
        *reinterpret_cast<half4*>(reinterpret_cast<char*>(Alds) + row * 1024 + bc) = hv;
    }
    __syncthreads();

    const int lane = threadIdx.x & 63, w = threadIdx.x >> 6;
    const int l15 = lane & 15, lg = lane >> 4;

    f32x4 acc[4][4];
    #pragma unroll
    for (int m = 0; m < 4; ++m)
        #pragma unroll
        for (int n = 0; n < 4; ++n)
            acc[m][n] = 0.0f;

    for (int kk = 0; kk < 16; ++kk) {
        half8 af[4], bf[4];
        #pragma unroll
        for (int m = 0; m < 4; ++m) {
            const int row = m * 16 + l15;
            const int bc = (kk * 64 + lg * 16) ^ ((row & 7) << 4);
            af[m] = *reinterpret_cast<const half8*>(
                reinterpret_cast<const char*>(Alds) + row * 1024 + bc);
        }
        #pragma unroll
        for (int n = 0; n < 4; ++n) {
            const int col = w * 64 + n * 16 + l15;
            bf[n] = *reinterpret_cast<const half8*>(wih16 + (size_t)col * 512 + kk * 32 + lg * 8);
        }
        #pragma unroll
        for (int m = 0; m < 4; ++m)
            #pragma unroll
            for (int n = 0; n < 4; ++n)
                acc[m][n] = __builtin_amdgcn_mfma_f32_16x16x32_f16(bf[n], af[m], acc[m][n], 0, 0, 0);
    }

    #pragma unroll
    for (int m = 0; m < 4; ++m) {
        const int brow = m * 16 + l15;
        #pragma unroll
        for (int n = 0; n < 4; ++n) {
            const int j0 = w * 64 + n * 16 + lg * 4;
            const float4 bv = *reinterpret_cast<const float4*>(bias + j0);
            half4 hv;
            hv[0] = (_Float16)(acc[m][n][0] + bv.x);
            hv[1] = (_Float16)(acc[m][n][1] + bv.y);
            hv[2] = (_Float16)(acc[m][n][2] + bv.z);
            hv[3] = (_Float16)(acc[m][n][3] + bv.w);
            *reinterpret_cast<half4*>(xp16 + ((size_t)s * 64 + brow) * 512 + j0) = hv;
        }
    }
}

// ---------------- recurrence: one WG per 8 batch rows, no cross-WG ----------------
__global__ __launch_bounds__(256, 1) void rnn_step_kernel(
    const _Float16* __restrict__ whh16, const _Float16* __restrict__ xp16,
    const float* __restrict__ state, float* __restrict__ out)
{
    extern __shared__ __align__(16) char smem[];
    char* wlds   = smem;                 // 16 chunks x 8208
    char* hbbase = smem + WLDS_SZ;       // 2 x 8576

    const int r = blockIdx.x;            // 0..7: batch rows r*8..+8
    const int tid = threadIdx.x;
    const int lane = tid & 63, w = tid >> 6;   // 4 waves, wave w: j in [w*128, +128)
    const int l15 = lane & 15, lg = lane >> 4;
    const int row8 = l15 & 7;
    const bool primary = (l15 < 8);

    // --- stage W-LDS: k = 384..511 as 16 chunks [(kk-12)*4+lgc][j=512][16B] ---
    for (int idx = tid; idx < NCHUNK * 512; idx += 256) {
        const int c = idx >> 9, j = idx & 511;
        const int kk = 12 + (c >> 2), lgc = c & 3;
        *reinterpret_cast<half8*>(wlds + c * WCHUNK + j * 16) =
            *reinterpret_cast<const half8*>(whh16 + (size_t)j * 512 + kk * 32 + lgc * 8);
    }
    // --- stage hbuf[0] = fp16(state rows r*8..+8) ---
    for (int idx = tid; idx < 1024; idx += 256) {
        const int row = idx >> 7, jc = idx & 127;
        const float4 v = *reinterpret_cast<const float4*>(
            state + (size_t)(r * 8 + row) * 512 + jc * 4);
        half4 hv;
        hv[0] = (_Float16)v.x; hv[1] = (_Float16)v.y;
        hv[2] = (_Float16)v.z; hv[3] = (_Float16)v.w;
        *reinterpret_cast<half4*>(hbbase + row * HSTRIDE + jc * 8) = hv;
    }

    // --- register W fragments: kk 0..11 (96 frags = 384 VGPR), static indices only ---
    half8 wreg[96];
    {
        const _Float16* wp = whh16 + (size_t)(w * 128 + l15) * 512 + lg * 8;
        #pragma unroll
        for (int jt = 0; jt < 8; ++jt)
            #pragma unroll
            for (int kk = 0; kk < 12; ++kk)
                wreg[jt * 12 + kk] = *reinterpret_cast<const half8*>(wp + jt * 16 * 512 + kk * 32);
    }

    // --- xp prefetch for t=0 (8 x u64 per lane) ---
    u64 xq[8];
    {
        const _Float16* xpb = xp16 + (size_t)(r * 8 + row8) * 512 + w * 128 + lg * 4;
        #pragma unroll
        for (int jt = 0; jt < 8; ++jt)
            xq[jt] = *reinterpret_cast<const u64*>(xpb + jt * 16);
    }

    __syncthreads();

    #pragma unroll 1
    for (int t = 0; t < S_SZ; ++t) {
        const char* hcur = hbbase + (t & 1) * HBUF_SZ;
        char* hnxt = hbbase + ((t + 1) & 1) * HBUF_SZ;

        f32x4 acc[8];
        #pragma unroll
        for (int jt = 0; jt < 8; ++jt) acc[jt] = 0.0f;

        // k = 0..383 from registers
        #pragma unroll
        for (int kk = 0; kk < 12; ++kk) {
            const half8 bf = *reinterpret_cast<const half8*>(
                hcur + row8 * HSTRIDE + kk * 64 + lg * 16);
            #pragma unroll
            for (int jt = 0; jt < 8; ++jt)
                acc[jt] = __builtin_amdgcn_mfma_f32_16x16x32_f16(wreg[jt * 12 + kk], bf, acc[jt], 0, 0, 0);
        }
        // k = 384..511 from LDS
        #pragma unroll
        for (int kk = 12; kk < 16; ++kk) {
            const half8 bf = *reinterpret_cast<const half8*>(
                hcur + row8 * HSTRIDE + kk * 64 + lg * 16);
            const char* wc = wlds + ((kk - 12) * 4 + lg) * WCHUNK + (w * 128 + l15) * 16;
            #pragma unroll
            for (int jt = 0; jt < 8; ++jt) {
                const half8 a = *reinterpret_cast<const half8*>(wc + jt * 256);
                acc[jt] = __builtin_amdgcn_mfma_f32_16x16x32_f16(a, bf, acc[jt], 0, 0, 0);
            }
        }

        // tanh + h-write + out-write
        const int orow_idx = r * 8 + l15;   // valid for primary lanes
        float* orow = out + ((size_t)t * 64 + orow_idx) * 512 + w * 128 + lg * 4;
        #pragma unroll
        for (int jt = 0; jt < 8; ++jt) {
            union { _Float16 h[4]; u64 u; } xv, hp;
            xv.u = xq[jt];
            f32x4 f;
            #pragma unroll
            for (int q = 0; q < 4; ++q) {
                f[q] = fast_tanh(acc[jt][q] + (float)xv.h[q]);
                hp.h[q] = (_Float16)f[q];
            }
            if (primary) {
                *reinterpret_cast<u64*>(hnxt + l15 * HSTRIDE + (w * 128 + jt * 16 + lg * 4) * 2) = hp.u;
                *reinterpret_cast<f32x4*>(orow + jt * 16) = f;
                if (t == S_SZ - 1) {
                    const int j0 = w * 128 + jt * 16 + lg * 4;
                    #pragma unroll
                    for (int q = 0; q < 4; ++q)
                        out[OUT1_OFF + (size_t)(j0 + q) * 64 + orow_idx] = f[q];
                }
            }
        }

        // reissue xp loads for t+1 (latency hides across the barrier + next MFMA phase)
        if (t + 1 < S_SZ) {
            const _Float16* xpb = xp16 + ((size_t)(t + 1) * 64 + r * 8 + row8) * 512 + w * 128 + lg * 4;
            #pragma unroll
            for (int jt = 0; jt < 8; ++jt)
                xq[jt] = *reinterpret_cast<const u64*>(xpb + jt * 16);
        }

        __syncthreads();
    }
}

extern "C" void kernel_launch(void* const* d_in, const int* in_sizes, int n_in,
                              void* d_out, int out_size, void* d_ws, size_t ws_size,
                              hipStream_t stream)
{
    const float* inputs = (const float*)d_in[0];
    const float* state  = (const float*)d_in[1];
    const float* w_ih   = (const float*)d_in[2];
    const float* b_ih   = (const float*)d_in[3];
    const float* w_hh   = (const float*)d_in[4];
    const float* b_hh   = (const float*)d_in[5];
    float* out = (float*)d_out;
    char* ws = (char*)d_ws;

    _Float16* xp16  = (_Float16*)(ws + XP_OFF);
    _Float16* whh16 = (_Float16*)(ws + WHH_OFF);
    _Float16* wih16 = (_Float16*)(ws + WIH_OFF);
    float*    bias  = (float*)(ws + BIAS_OFF);

    // allow 148 KB dynamic LDS for the rnn kernel (idempotent; capture-safe)
    hipFuncSetAttribute((const void*)rnn_step_kernel,
                        hipFuncAttributeMaxDynamicSharedMemorySize, SMEM_SZ);

    prep_kernel<<<1024, 256, 0, stream>>>(w_ih, w_hh, b_ih, b_hh, wih16, whh16, bias);
    xproj_kernel<<<S_SZ, 512, 0, stream>>>(inputs, wih16, bias, xp16);
    rnn_step_kernel<<<8, 256, SMEM_SZ, stream>>>(whh16, xp16, state, out);
}

// Round 8
// 6975.323 us; speedup vs baseline: 7.2749x; 1.1018x over previous
//
#include <hip/hip_runtime.h>

// Tanh RNN: B=64, S=2048, I=H=512, fp32 in/out.
//
// Round 8: round-6/7 structure (8 WGs, zero inter-WG comm; WG r owns batch
// rows r*8..+8 and the FULL j range). Weight residency WITHOUT inline-asm
// MFMA (round 7's failure: raw asm MFMA bypasses the compiler's hazard
// s_nop insertion). All MFMAs are builtins; weight fragments are pinned to
// register classes with empty-asm constraints:
//   kk 0..7   (k 0..255)  : 64 half8 frags pinned "+a"  -> AGPR file (256)
//   kk 8..11  (k 256..383): 32 half8 frags pinned "+v"  -> VGPRs    (128)
//   kk 12..15 (k 384..511): LDS chunks (131 KB), linear layout
// h double-buffer in LDS as [kk][lg][row] 16B entries (bank-even, verified
// mapping). One __syncthreads per step. 4 waves/WG, wave w owns j in
// [w*128, +128).

typedef _Float16 half8 __attribute__((ext_vector_type(8)));
typedef _Float16 half4 __attribute__((ext_vector_type(4)));
typedef float f32x4 __attribute__((ext_vector_type(4)));
typedef unsigned long long u64;

#define S_SZ 2048
#define OUT1_OFF 67108864ull   // S*B*H floats

// workspace offsets (bytes)
#define XP_OFF    0ull              // 2048*64*512*2 = 134217728
#define WHH_OFF   134217728ull      // 524288
#define WIH_OFF   134742016ull      // 524288
#define BIAS_OFF  135266304ull      // 2048

#define WLDS_SZ   131072            // 16 chunks * 8192 B (kk 12..15 x lg 0..3)
#define HB_SZ     8192              // one h buffer: 16kk*4lg*8row*16B
#define SMEM_SZ   147456            // WLDS + 2*HB

__device__ __forceinline__ float fast_tanh(float x) {
    float a = exp2f(x * 2.8853900817779268f);
    return (a - 1.0f) * __builtin_amdgcn_rcpf(a + 1.0f);
}

__global__ void prep_kernel(const float* __restrict__ wih, const float* __restrict__ whh,
                            const float* __restrict__ bih, const float* __restrict__ bhh,
                            _Float16* __restrict__ wih16, _Float16* __restrict__ whh16,
                            float* __restrict__ bias)
{
    const int i = blockIdx.x * 256 + threadIdx.x;   // 1024 blocks -> 262144
    wih16[i] = (_Float16)wih[i];
    whh16[i] = (_Float16)whh[i];
    if (i < 512) bias[i] = bih[i] + bhh[i];
}

// ---------------- input projection GEMM (verified rounds 3-6) ----------------
__global__ __launch_bounds__(512, 1) void xproj_kernel(
    const float* __restrict__ inputs, const _Float16* __restrict__ wih16,
    const float* __restrict__ bias, _Float16* __restrict__ xp16)
{
    __shared__ _Float16 Alds[64 * 512];
    const int s = blockIdx.x;

    for (int idx = threadIdx.x; idx < 64 * 128; idx += 512) {
        const int row = idx >> 7, chunk = idx & 127;
        const float4 v = *reinterpret_cast<const float4*>(
            inputs + ((size_t)row * S_SZ + s) * 512 + chunk * 4);
        half4 hv;
        hv[0] = (_Float16)v.x; hv[1] = (_Float16)v.y;
        hv[2] = (_Float16)v.z; hv[3] = (_Float16)v.w;
        const int bc = (chunk * 8) ^ ((row & 7) << 4);
        *reinterpret_cast<half4*>(reinterpret_cast<char*>(Alds) + row * 1024 + bc) = hv;
    }
    __syncthreads();

    const int lane = threadIdx.x & 63, w = threadIdx.x >> 6;
    const int l15 = lane & 15, lg = lane >> 4;

    f32x4 acc[4][4];
    #pragma unroll
    for (int m = 0; m < 4; ++m)
        #pragma unroll
        for (int n = 0; n < 4; ++n)
            acc[m][n] = 0.0f;

    for (int kk = 0; kk < 16; ++kk) {
        half8 af[4], bf[4];
        #pragma unroll
        for (int m = 0; m < 4; ++m) {
            const int row = m * 16 + l15;
            const int bc = (kk * 64 + lg * 16) ^ ((row & 7) << 4);
            af[m] = *reinterpret_cast<const half8*>(
                reinterpret_cast<const char*>(Alds) + row * 1024 + bc);
        }
        #pragma unroll
        for (int n = 0; n < 4; ++n) {
            const int col = w * 64 + n * 16 + l15;
            bf[n] = *reinterpret_cast<const half8*>(wih16 + (size_t)col * 512 + kk * 32 + lg * 8);
        }
        #pragma unroll
        for (int m = 0; m < 4; ++m)
            #pragma unroll
            for (int n = 0; n < 4; ++n)
                acc[m][n] = __builtin_amdgcn_mfma_f32_16x16x32_f16(bf[n], af[m], acc[m][n], 0, 0, 0);
    }

    #pragma unroll
    for (int m = 0; m < 4; ++m) {
        const int brow = m * 16 + l15;
        #pragma unroll
        for (int n = 0; n < 4; ++n) {
            const int j0 = w * 64 + n * 16 + lg * 4;
            const float4 bv = *reinterpret_cast<const float4*>(bias + j0);
            half4 hv;
            hv[0] = (_Float16)(acc[m][n][0] + bv.x);
            hv[1] = (_Float16)(acc[m][n][1] + bv.y);
            hv[2] = (_Float16)(acc[m][n][2] + bv.z);
            hv[3] = (_Float16)(acc[m][n][3] + bv.w);
            *reinterpret_cast<half4*>(xp16 + ((size_t)s * 64 + brow) * 512 + j0) = hv;
        }
    }
}

// ---------------- recurrence: pinned-register weights, builtin MFMA ----------------
__global__ __launch_bounds__(256, 1) void rnn_step_kernel(
    const _Float16* __restrict__ whh16, const _Float16* __restrict__ xp16,
    const float* __restrict__ state, float* __restrict__ out)
{
    extern __shared__ __align__(16) char smem[];
    char* wlds = smem;                 // 16 chunks * 8192
    char* hb   = smem + WLDS_SZ;       // 2 * 8192

    const int r = blockIdx.x;          // 0..7: batch rows r*8..+8
    const int tid = threadIdx.x;
    const int lane = tid & 63, w = tid >> 6;   // 4 waves; wave w: j in [w*128, +128)
    const int l15 = lane & 15, lg = lane >> 4;
    const int row8 = l15 & 7;
    const bool primary = (l15 < 8);

    // --- stage W-LDS (kk 12..15), linear: chunk c=(kk-12)*4+lgc, entry jj ---
    for (int idx = tid; idx < 16 * 512; idx += 256) {
        const int c = idx >> 9, jj = idx & 511;
        const int kk = 12 + (c >> 2), lgc = c & 3;
        *reinterpret_cast<half8*>(wlds + c * 8192 + jj * 16) =
            *reinterpret_cast<const half8*>(whh16 + (size_t)jj * 512 + kk * 32 + lgc * 8);
    }
    // --- stage h0 as [kk][lg][row] entries: h[row][kk*32+lg*8 .. +8] ---
    for (int idx = tid; idx < 512; idx += 256) {
        const int row = idx & 7, lgc = (idx >> 3) & 3, kk = idx >> 5;
        const float* sp = state + (size_t)(r * 8 + row) * 512 + kk * 32 + lgc * 8;
        const float4 v0 = *reinterpret_cast<const float4*>(sp);
        const float4 v1 = *reinterpret_cast<const float4*>(sp + 4);
        half8 hv;
        hv[0] = (_Float16)v0.x; hv[1] = (_Float16)v0.y;
        hv[2] = (_Float16)v0.z; hv[3] = (_Float16)v0.w;
        hv[4] = (_Float16)v1.x; hv[5] = (_Float16)v1.y;
        hv[6] = (_Float16)v1.z; hv[7] = (_Float16)v1.w;
        *reinterpret_cast<half8*>(hb + ((kk * 4 + lgc) * 8 + row) * 16) = hv;
    }

    // --- register weights: wa (kk 0..7 -> AGPR) + wv (kk 8..11 -> VGPR) ---
    half8 wa[64], wv[32];
    {
        const _Float16* wp = whh16 + (size_t)(w * 128 + l15) * 512 + lg * 8;
        #pragma unroll
        for (int jt = 0; jt < 8; ++jt) {
            #pragma unroll
            for (int kk = 0; kk < 8; ++kk)
                wa[jt * 8 + kk] = *reinterpret_cast<const half8*>(wp + jt * 16 * 512 + kk * 32);
            #pragma unroll
            for (int kk = 8; kk < 12; ++kk)
                wv[jt * 4 + kk - 8] = *reinterpret_cast<const half8*>(wp + jt * 16 * 512 + kk * 32);
        }
    }
    // pin: opaque def blocks remat; "a"/"v" fixes the register class.
    // All MFMAs below are BUILTINS (compiler owns hazards/waitcnt) and can
    // read the A operand directly from AGPRs (gfx950 unified file).
    #pragma unroll
    for (int i = 0; i < 64; ++i) asm volatile("" : "+a"(wa[i]));
    #pragma unroll
    for (int i = 0; i < 32; ++i) asm volatile("" : "+v"(wv[i]));

    // --- xp prefetch for t=0 ---
    u64 xq[8];
    {
        const _Float16* xpb = xp16 + (size_t)(r * 8 + row8) * 512 + w * 128 + lg * 4;
        #pragma unroll
        for (int jt = 0; jt < 8; ++jt)
            xq[jt] = *reinterpret_cast<const u64*>(xpb + jt * 16);
    }

    __syncthreads();

    #pragma unroll 1
    for (int t = 0; t < S_SZ; ++t) {
        const char* hc = hb + (t & 1) * HB_SZ;
        char* hn = hb + ((t + 1) & 1) * HB_SZ;

        f32x4 acc[8];
        #pragma unroll
        for (int jt = 0; jt < 8; ++jt) acc[jt] = 0.0f;

        // kk 0..7: AGPR-resident weights (builtin, A from AGPR)
        #pragma unroll
        for (int kk = 0; kk < 8; ++kk) {
            const half8 bf = *reinterpret_cast<const half8*>(
                hc + ((kk * 4 + lg) * 8 + row8) * 16);
            #pragma unroll
            for (int jt = 0; jt < 8; ++jt)
                acc[jt] = __builtin_amdgcn_mfma_f32_16x16x32_f16(
                    wa[jt * 8 + kk], bf, acc[jt], 0, 0, 0);
        }
        // kk 8..11: VGPR-resident weights
        #pragma unroll
        for (int kk = 8; kk < 12; ++kk) {
            const half8 bf = *reinterpret_cast<const half8*>(
                hc + ((kk * 4 + lg) * 8 + row8) * 16);
            #pragma unroll
            for (int jt = 0; jt < 8; ++jt)
                acc[jt] = __builtin_amdgcn_mfma_f32_16x16x32_f16(
                    wv[jt * 4 + kk - 8], bf, acc[jt], 0, 0, 0);
        }
        // kk 12..15: weights from LDS
        #pragma unroll
        for (int kk = 12; kk < 16; ++kk) {
            const half8 bf = *reinterpret_cast<const half8*>(
                hc + ((kk * 4 + lg) * 8 + row8) * 16);
            const char* wc = wlds + ((kk - 12) * 4 + lg) * 8192;
            #pragma unroll
            for (int jt = 0; jt < 8; ++jt) {
                const half8 a = *reinterpret_cast<const half8*>(
                    wc + (w * 128 + jt * 16 + l15) * 16);
                acc[jt] = __builtin_amdgcn_mfma_f32_16x16x32_f16(a, bf, acc[jt], 0, 0, 0);
            }
        }

        // ---- tanh + h-write (layout [kk][lg][row]) + out stores ----
        const int orow_idx = r * 8 + l15;
        float* orow = out + ((size_t)t * 64 + orow_idx) * 512 + w * 128 + lg * 4;
        #pragma unroll
        for (int jt = 0; jt < 8; ++jt) {
            union { _Float16 h[4]; u64 u; } xv, hp;
            xv.u = xq[jt];
            f32x4 f;
            #pragma unroll
            for (int q = 0; q < 4; ++q) {
                f[q] = fast_tanh(acc[jt][q] + (float)xv.h[q]);
                hp.h[q] = (_Float16)f[q];
            }
            if (primary) {
                // j0 = w*128 + jt*16 + lg*4 -> entry ((w*4+(jt>>1))*4 + 2*(jt&1)+(lg>>1), row l15)
                const int e = ((w * 4 + (jt >> 1)) * 4 + 2 * (jt & 1) + (lg >> 1)) * 8 + l15;
                *reinterpret_cast<u64*>(hn + e * 16 + (lg & 1) * 8) = hp.u;
                *reinterpret_cast<f32x4*>(orow + jt * 16) = f;
                if (t == S_SZ - 1) {
                    const int j0 = w * 128 + jt * 16 + lg * 4;
                    #pragma unroll
                    for (int q = 0; q < 4; ++q)
                        out[OUT1_OFF + (size_t)(j0 + q) * 64 + orow_idx] = f[q];
                }
            }
        }

        // ---- xp prefetch for t+1 ----
        if (t + 1 < S_SZ) {
            const _Float16* xpb = xp16 + ((size_t)(t + 1) * 64 + r * 8 + row8) * 512 + w * 128 + lg * 4;
            #pragma unroll
            for (int jt = 0; jt < 8; ++jt)
                xq[jt] = *reinterpret_cast<const u64*>(xpb + jt * 16);
        }

        __syncthreads();
    }
}

extern "C" void kernel_launch(void* const* d_in, const int* in_sizes, int n_in,
                              void* d_out, int out_size, void* d_ws, size_t ws_size,
                              hipStream_t stream)
{
    const float* inputs = (const float*)d_in[0];
    const float* state  = (const float*)d_in[1];
    const float* w_ih   = (const float*)d_in[2];
    const float* b_ih   = (const float*)d_in[3];
    const float* w_hh   = (const float*)d_in[4];
    const float* b_hh   = (const float*)d_in[5];
    float* out = (float*)d_out;
    char* ws = (char*)d_ws;

    _Float16* xp16  = (_Float16*)(ws + XP_OFF);
    _Float16* whh16 = (_Float16*)(ws + WHH_OFF);
    _Float16* wih16 = (_Float16*)(ws + WIH_OFF);
    float*    bias  = (float*)(ws + BIAS_OFF);

    hipFuncSetAttribute((const void*)rnn_step_kernel,
                        hipFuncAttributeMaxDynamicSharedMemorySize, SMEM_SZ);

    prep_kernel<<<1024, 256, 0, stream>>>(w_ih, w_hh, b_ih, b_hh, wih16, whh16, bias);
    xproj_kernel<<<S_SZ, 512, 0, stream>>>(inputs, wih16, bias, xp16);
    rnn_step_kernel<<<8, 256, SMEM_SZ, stream>>>(whh16, xp16, state, out);
}